// Round 16
// baseline (30.918 us; speedup 1.0000x reference)
//
#include <hip/hip_runtime.h>

#define B 4
#define NQ 512
#define NK 512
#define D 128
#define H 32
#define G 4                              // queries per attend block
#define PS 2.8853900817779268f           // 2*log2(e)
#define NKP (NK + 8)                     // padded ex row: breaks 4-way bank alias

typedef float f32x4 __attribute__((ext_vector_type(4)));
typedef short bf16x8 __attribute__((ext_vector_type(8)));

__device__ __forceinline__ float rcp_f(float x)  { return __builtin_amdgcn_rcpf(x); }
__device__ __forceinline__ float exp2_f(float x) { return __builtin_amdgcn_exp2f(x); }

// fp32 -> truncated bf16 hi + bf16 lo (combined rel err ~2^-16)
__device__ __forceinline__ void bf16_split(float x, unsigned short& h, unsigned short& l) {
    unsigned bits = __float_as_uint(x);
    h = (unsigned short)(bits >> 16);
    float hf = __uint_as_float((unsigned)h << 16);
    l = (unsigned short)(__float_as_uint(x - hf) >> 16);
}

// Ek[b][h][k] = exp2(PS*(keys.Wk + b1)) (transposed); eq[b][q][h] = exp2(PS*(queries.Wq));
// NEW: keys_hi/lo[b][d][k] bf16-split transposed copies of keys for MFMA B-operand.
__global__ __launch_bounds__(256) void proj_kernel(
    const float* __restrict__ keys, const float* __restrict__ queries,
    const float* __restrict__ Wk, const float* __restrict__ Wq,
    const float* __restrict__ b1,
    float* __restrict__ Ek, float* __restrict__ eq,
    unsigned short* __restrict__ khi, unsigned short* __restrict__ klo)
{
    __shared__ float xs[8][D];
    const int tid = threadIdx.x;
    const int r0 = blockIdx.x * 8;
    const bool is_q = (r0 >= B * NK);
    const float* __restrict__ X = is_q ? (queries + (size_t)(r0 - B * NK) * D)
                                       : (keys + (size_t)r0 * D);
    const float* __restrict__ W = is_q ? Wq : Wk;

    reinterpret_cast<float4*>(&xs[0][0])[tid] =
        reinterpret_cast<const float4*>(X)[tid];
    __syncthreads();

    const int lr = tid >> 5;
    const int h  = tid & 31;
    float a0 = 0.f, a1 = 0.f, a2 = 0.f, a3 = 0.f;
    const float4* x4 = reinterpret_cast<const float4*>(&xs[lr][0]);
    #pragma unroll
    for (int i = 0; i < D / 4; ++i) {
        float4 v = x4[i];
        a0 = fmaf(v.x, W[(4 * i + 0) * H + h], a0);
        a1 = fmaf(v.y, W[(4 * i + 1) * H + h], a1);
        a2 = fmaf(v.z, W[(4 * i + 2) * H + h], a2);
        a3 = fmaf(v.w, W[(4 * i + 3) * H + h], a3);
    }
    float acc = (a0 + a1) + (a2 + a3);
    if (is_q) {
        const int rq = r0 - B * NK + lr;
        eq[(size_t)rq * H + h] = exp2_f(acc * PS);
    } else {
        const int r = r0 + lr;
        const int b = r >> 9;
        const int k = r & (NK - 1);
        Ek[((size_t)b * H + h) * NK + k] = exp2_f((acc + b1[h]) * PS);
    }

    // bf16-split transposed keys for the MFMA path (key-blocks only)
    if (!is_q) {
        const int bb = r0 >> 9;
        const int k0 = r0 & (NK - 1);
        const int d  = tid >> 1;
        const int kq = (tid & 1) * 4;
        ushort4 h4, l4;
        unsigned short* hp = reinterpret_cast<unsigned short*>(&h4);
        unsigned short* lp = reinterpret_cast<unsigned short*>(&l4);
        #pragma unroll
        for (int j = 0; j < 4; ++j)
            bf16_split(xs[kq + j][d], hp[j], lp[j]);
        *reinterpret_cast<ushort4*>(&khi[((size_t)bb * D + d) * NK + k0 + kq]) = h4;
        *reinterpret_cast<ushort4*>(&klo[((size_t)bb * D + d) * NK + k0 + kq]) = l4;
    }
}

// One block per (b, G=4 queries). 512 threads. Ph1 = r15 (prefetch + rational
// combine). Ph2 = MFMA: wave w computes out[0..3][w*16..w*16+15] via
// 16 K-steps x 3 bf16-split mfma_f32_16x16x32_bf16. No accm, no partition reduce.
__global__ __launch_bounds__(512, 4) void attend_kernel(
    const unsigned short* __restrict__ khi,  // [B][D][NK] bf16 hi
    const unsigned short* __restrict__ klo,  // [B][D][NK] bf16 lo
    const float* __restrict__ Ek,            // [B][H][NK]
    const float* __restrict__ eq,            // [B][NQ][H]
    const float* __restrict__ w2,
    float* __restrict__ outp)
{
    __shared__ unsigned short ex_hi[G][NKP]; // 4.1 KB  normalized weights, bf16 hi
    __shared__ unsigned short ex_lo[G][NKP]; // 4.1 KB  bf16 lo
    __shared__ float red[8][G];

    const int tid = threadIdx.x;
    const int b   = blockIdx.x >> 7;
    const int q0  = (blockIdx.x & 127) * G;

    // ---- phase 1: prefetch all 32 Ek column values, rational-combine logits
    const float* Ekc = Ek + (size_t)b * H * NK + tid;
    float ek[H];
    #pragma unroll
    for (int h = 0; h < H; ++h) ek[h] = Ekc[h * NK];   // 32 outstanding loads

    const float* eqb = eq + ((size_t)b * NQ + q0) * H;   // uniform -> s_load
    float acc[G];
    #pragma unroll
    for (int g = 0; g < G; ++g) acc[g] = 0.f;

    #pragma unroll
    for (int h4 = 0; h4 < H; h4 += 4) {
        const float w0 = w2[h4 + 0];
        const float w1 = w2[h4 + 1];
        const float wc = w2[h4 + 2];
        const float w3 = w2[h4 + 3];
        #pragma unroll
        for (int g = 0; g < G; ++g) {
            const float d0 = fmaf(eqb[g * H + h4 + 0], ek[h4 + 0], 1.f);
            const float d1 = fmaf(eqb[g * H + h4 + 1], ek[h4 + 1], 1.f);
            const float d2 = fmaf(eqb[g * H + h4 + 2], ek[h4 + 2], 1.f);
            const float d3 = fmaf(eqb[g * H + h4 + 3], ek[h4 + 3], 1.f);
            const float nab = fmaf(w1, d0, w0 * d1);
            const float ncd = fmaf(w3, d2, wc * d3);
            const float dab = d0 * d1;
            const float dcd = d2 * d3;
            const float n4  = fmaf(nab, dcd, ncd * dab);
            acc[g] = fmaf(n4, rcp_f(dab * dcd), acc[g]);   // ONE rcp per 4 h's
        }
    }
    // exponent = -PS*acc (const dropped; |exponent| <= 16.3 -> no max pass)
    float e0 = exp2_f(-PS * acc[0]);
    float e1 = exp2_f(-PS * acc[1]);
    float e2 = exp2_f(-PS * acc[2]);
    float e3 = exp2_f(-PS * acc[3]);

    // ---- block sum over k
    float s0 = e0, s1 = e1, s2 = e2, s3 = e3;
    #pragma unroll
    for (int off = 32; off; off >>= 1) {
        s0 += __shfl_xor(s0, off);
        s1 += __shfl_xor(s1, off);
        s2 += __shfl_xor(s2, off);
        s3 += __shfl_xor(s3, off);
    }
    if ((tid & 63) == 0)
        *reinterpret_cast<float4*>(&red[tid >> 6][0]) = float4{s0, s1, s2, s3};
    __syncthreads();
    float4 sum = {0.f, 0.f, 0.f, 0.f};
    #pragma unroll
    for (int p = 0; p < 8; ++p) {
        const float4 v = *reinterpret_cast<const float4*>(&red[p][0]);  // broadcast
        sum.x += v.x; sum.y += v.y; sum.z += v.z; sum.w += v.w;
    }
    // normalized weights -> bf16 split in LDS (thread owns key k = tid)
    {
        const float v0 = e0 * rcp_f(sum.x);
        const float v1 = e1 * rcp_f(sum.y);
        const float v2 = e2 * rcp_f(sum.z);
        const float v3 = e3 * rcp_f(sum.w);
        unsigned short h, l;
        bf16_split(v0, h, l); ex_hi[0][tid] = h; ex_lo[0][tid] = l;
        bf16_split(v1, h, l); ex_hi[1][tid] = h; ex_lo[1][tid] = l;
        bf16_split(v2, h, l); ex_hi[2][tid] = h; ex_lo[2][tid] = l;
        bf16_split(v3, h, l); ex_hi[3][tid] = h; ex_lo[3][tid] = l;
    }
    __syncthreads();

    // ---- phase 2: MFMA context. wave w -> cols [w*16, w*16+16).
    // A[16][32] rows 0-15 map to ex rows (row & 3): rows 4-15 are harmless dups.
    const int lane = tid & 63;
    const int w    = tid >> 6;
    const int kgrp = lane >> 4;              // K-offset group (8 k each)
    const int dcol = w * 16 + (lane & 15);
    const unsigned short* bh_base = khi + ((size_t)b * D + dcol) * NK;
    const unsigned short* bl_base = klo + ((size_t)b * D + dcol) * NK;

    f32x4 c = {0.f, 0.f, 0.f, 0.f};
    #pragma unroll 4
    for (int s = 0; s < 16; ++s) {
        const int ko = s * 32 + kgrp * 8;
        const bf16x8 ah = *reinterpret_cast<const bf16x8*>(&ex_hi[lane & 3][ko]);
        const bf16x8 al = *reinterpret_cast<const bf16x8*>(&ex_lo[lane & 3][ko]);
        const bf16x8 bh = *reinterpret_cast<const bf16x8*>(bh_base + ko);
        const bf16x8 bl = *reinterpret_cast<const bf16x8*>(bl_base + ko);
        c = __builtin_amdgcn_mfma_f32_16x16x32_bf16(ah, bh, c, 0, 0, 0);
        c = __builtin_amdgcn_mfma_f32_16x16x32_bf16(al, bh, c, 0, 0, 0);
        c = __builtin_amdgcn_mfma_f32_16x16x32_bf16(ah, bl, c, 0, 0, 0);
    }
    // C/D: col = lane&15, row = (lane>>4)*4 + reg  [m89]; rows 0-3 live in lanes 0-15
    if (kgrp == 0) {
        #pragma unroll
        for (int r = 0; r < 4; ++r)
            outp[((size_t)b * NQ + q0 + r) * D + dcol] = c[r];
    }
}

extern "C" void kernel_launch(void* const* d_in, const int* in_sizes, int n_in,
                              void* d_out, int out_size, void* d_ws, size_t ws_size,
                              hipStream_t stream) {
    const float* keys    = (const float*)d_in[0];
    const float* queries = (const float*)d_in[1];
    const float* Wk      = (const float*)d_in[2];
    const float* Wq      = (const float*)d_in[3];
    const float* b1      = (const float*)d_in[4];
    const float* w2      = (const float*)d_in[5];
    // d_in[6] = b2: dropped (softmax shift-invariant)
    float* out = (float*)d_out;

    float* Ek = (float*)d_ws;                               // 256 KB
    float* eq = Ek + (size_t)B * H * NK;                    // 256 KB
    unsigned short* khi = (unsigned short*)(eq + (size_t)B * NQ * H);  // 512 KB
    unsigned short* klo = khi + (size_t)B * D * NK;                    // 512 KB

    const int proj_blocks = (B * NK + B * NQ) / 8;   // 512
    proj_kernel<<<proj_blocks, 256, 0, stream>>>(keys, queries, Wk, Wq, b1,
                                                 Ek, eq, khi, klo);
    attend_kernel<<<B * NQ / G, 512, 0, stream>>>(khi, klo, Ek, eq, w2, out);
}

// Round 17
// 20.583 us; speedup vs baseline: 1.5021x; 1.5021x over previous
//
#include <hip/hip_runtime.h>

#define B 4
#define NQ 512
#define NK 512
#define D 128
#define H 32
#define G 4                              // queries per attend block
#define PS 2.8853900817779268f           // 2*log2(e)

__device__ __forceinline__ float rcp_f(float x)  { return __builtin_amdgcn_rcpf(x); }
__device__ __forceinline__ float exp2_f(float x) { return __builtin_amdgcn_exp2f(x); }

__device__ __forceinline__ void fma4(float4& a, const float4& v, float s) {
    a.x = fmaf(s, v.x, a.x);
    a.y = fmaf(s, v.y, a.y);
    a.z = fmaf(s, v.z, a.z);
    a.w = fmaf(s, v.w, a.w);
}

// Ek[b][h][k] = exp2(PS*(keys[b,k,:].Wk[:,h] + b1[h]))   (transposed)
// eq[b][q][h] = exp2(PS*(queries[b,q,:].Wq[:,h]))
__global__ __launch_bounds__(256) void proj_kernel(
    const float* __restrict__ keys, const float* __restrict__ queries,
    const float* __restrict__ Wk, const float* __restrict__ Wq,
    const float* __restrict__ b1,
    float* __restrict__ Ek, float* __restrict__ eq)
{
    __shared__ float xs[8][D];
    const int tid = threadIdx.x;
    const int r0 = blockIdx.x * 8;
    const bool is_q = (r0 >= B * NK);
    const float* __restrict__ X = is_q ? (queries + (size_t)(r0 - B * NK) * D)
                                       : (keys + (size_t)r0 * D);
    const float* __restrict__ W = is_q ? Wq : Wk;

    reinterpret_cast<float4*>(&xs[0][0])[tid] =
        reinterpret_cast<const float4*>(X)[tid];
    __syncthreads();

    const int lr = tid >> 5;
    const int h  = tid & 31;
    float a0 = 0.f, a1 = 0.f, a2 = 0.f, a3 = 0.f;
    const float4* x4 = reinterpret_cast<const float4*>(&xs[lr][0]);
    #pragma unroll
    for (int i = 0; i < D / 4; ++i) {
        float4 v = x4[i];
        a0 = fmaf(v.x, W[(4 * i + 0) * H + h], a0);
        a1 = fmaf(v.y, W[(4 * i + 1) * H + h], a1);
        a2 = fmaf(v.z, W[(4 * i + 2) * H + h], a2);
        a3 = fmaf(v.w, W[(4 * i + 3) * H + h], a3);
    }
    float acc = (a0 + a1) + (a2 + a3);
    if (is_q) {
        const int rq = r0 - B * NK + lr;
        eq[(size_t)rq * H + h] = exp2_f(acc * PS);
    } else {
        const int r = r0 + lr;
        const int b = r >> 9;
        const int k = r & (NK - 1);
        Ek[((size_t)b * H + h) * NK + k] = exp2_f((acc + b1[h]) * PS);
    }
}

// One block per (b, G=4 queries). 512 threads. r15 math; NEW: phase-2's first
// keys chunk is issued AT KERNEL ENTRY (before Ek prefetch + phase 1), so the
// coldest misses overlap ~2000 cyc of phase-1 compute.
__global__ __launch_bounds__(512, 4) void attend_kernel(
    const float* __restrict__ keys,
    const float* __restrict__ Ek,     // [B][H][NK]
    const float* __restrict__ eq,     // [B][NQ][H]
    const float* __restrict__ w2,
    float* __restrict__ outp)
{
    __shared__ float exw[NK][G];      // 8 KB   normalized weights, [k][g]
    __shared__ float accm[16][G][D];  // 32 KB  ph2 partials; head doubles as red[8][G]
    float* red = &accm[0][0][0];

    const int tid = threadIdx.x;
    const int b   = blockIdx.x >> 7;
    const int q0  = (blockIdx.x & 127) * G;

    // ---- entry: issue keys chunk 0 (8 x float4) for phase 2 ----
    const int dg = tid & 31;
    const int kp = tid >> 5;
    const float4* k4 = reinterpret_cast<const float4*>(
        keys + ((size_t)b * NK + kp * 32) * D) + dg;
    float4 kbA[8], kbB[8];
    #pragma unroll
    for (int j = 0; j < 8; ++j) kbA[j] = k4[(size_t)j * (D / 4)];

    // ---- phase 1: prefetch all 32 Ek column values ----
    const float* Ekc = Ek + (size_t)b * H * NK + tid;
    float ek[H];
    #pragma unroll
    for (int h = 0; h < H; ++h) ek[h] = Ekc[h * NK];   // 32 outstanding b32 loads
    __builtin_amdgcn_sched_barrier(0);   // pin: all loads above are issued here

    const float* eqb = eq + ((size_t)b * NQ + q0) * H;   // uniform -> s_load
    float acc[G];
    #pragma unroll
    for (int g = 0; g < G; ++g) acc[g] = 0.f;

    #pragma unroll
    for (int h4 = 0; h4 < H; h4 += 4) {
        const float w0 = w2[h4 + 0];
        const float w1 = w2[h4 + 1];
        const float wc = w2[h4 + 2];
        const float w3 = w2[h4 + 3];
        #pragma unroll
        for (int g = 0; g < G; ++g) {
            const float d0 = fmaf(eqb[g * H + h4 + 0], ek[h4 + 0], 1.f);
            const float d1 = fmaf(eqb[g * H + h4 + 1], ek[h4 + 1], 1.f);
            const float d2 = fmaf(eqb[g * H + h4 + 2], ek[h4 + 2], 1.f);
            const float d3 = fmaf(eqb[g * H + h4 + 3], ek[h4 + 3], 1.f);
            const float nab = fmaf(w1, d0, w0 * d1);
            const float ncd = fmaf(w3, d2, wc * d3);
            const float dab = d0 * d1;
            const float dcd = d2 * d3;
            const float n4  = fmaf(nab, dcd, ncd * dab);
            acc[g] = fmaf(n4, rcp_f(dab * dcd), acc[g]);   // ONE rcp per 4 h's
        }
    }
    // exponent = -PS*acc (const dropped; |exponent| <= 16.3 -> no max pass)
    float e0 = exp2_f(-PS * acc[0]);
    float e1 = exp2_f(-PS * acc[1]);
    float e2 = exp2_f(-PS * acc[2]);
    float e3 = exp2_f(-PS * acc[3]);

    // ---- block sum over k (red aliases accm) ----
    float s0 = e0, s1 = e1, s2 = e2, s3 = e3;
    #pragma unroll
    for (int off = 32; off; off >>= 1) {
        s0 += __shfl_xor(s0, off);
        s1 += __shfl_xor(s1, off);
        s2 += __shfl_xor(s2, off);
        s3 += __shfl_xor(s3, off);
    }
    if ((tid & 63) == 0)
        *reinterpret_cast<float4*>(red + (tid >> 6) * G) = float4{s0, s1, s2, s3};
    __syncthreads();
    float4 sum = {0.f, 0.f, 0.f, 0.f};
    #pragma unroll
    for (int p = 0; p < 8; ++p) {
        const float4 v = *reinterpret_cast<const float4*>(red + p * G);  // broadcast
        sum.x += v.x; sum.y += v.y; sum.z += v.z; sum.w += v.w;
    }
    *reinterpret_cast<float4*>(&exw[tid][0]) =
        float4{e0 * rcp_f(sum.x), e1 * rcp_f(sum.y),
               e2 * rcp_f(sum.z), e3 * rcp_f(sum.w)};
    __syncthreads();    // red reads done -> accm may be overwritten in ph2

    // ---- phase 2: context; chunk 0 already in registers, rotate 8-deep ----
    float4 a0 = {0,0,0,0}, a1 = a0, a2 = a0, a3 = a0;
    #pragma unroll
    for (int c = 0; c < 4; ++c) {
        float4* cur = (c & 1) ? kbB : kbA;
        float4* nxt = (c & 1) ? kbA : kbB;
        if (c < 3) {
            #pragma unroll
            for (int j = 0; j < 8; ++j)
                nxt[j] = k4[(size_t)((c + 1) * 8 + j) * (D / 4)];   // issue next chunk
        }
        #pragma unroll
        for (int j = 0; j < 8; ++j) {
            const int kk = c * 8 + j;
            const float4 ev = *reinterpret_cast<const float4*>(&exw[kp * 32 + kk][0]);
            fma4(a0, cur[j], ev.x);
            fma4(a1, cur[j], ev.y);
            fma4(a2, cur[j], ev.z);
            fma4(a3, cur[j], ev.w);
        }
    }
    *reinterpret_cast<float4*>(&accm[kp][0][4 * dg]) = a0;
    *reinterpret_cast<float4*>(&accm[kp][1][4 * dg]) = a1;
    *reinterpret_cast<float4*>(&accm[kp][2][4 * dg]) = a2;
    *reinterpret_cast<float4*>(&accm[kp][3][4 * dg]) = a3;
    __syncthreads();

    // ---- reduce 16 partitions; thread t -> output (g,d) ----
    const int g = tid >> 7;
    const int d = tid & 127;
    float r = 0.f;
    #pragma unroll
    for (int p = 0; p < 16; ++p) r += accm[p][g][d];
    outp[((size_t)b * NQ + q0 + g) * D + d] = r;
}

extern "C" void kernel_launch(void* const* d_in, const int* in_sizes, int n_in,
                              void* d_out, int out_size, void* d_ws, size_t ws_size,
                              hipStream_t stream) {
    const float* keys    = (const float*)d_in[0];
    const float* queries = (const float*)d_in[1];
    const float* Wk      = (const float*)d_in[2];
    const float* Wq      = (const float*)d_in[3];
    const float* b1      = (const float*)d_in[4];
    const float* w2      = (const float*)d_in[5];
    // d_in[6] = b2: dropped (softmax shift-invariant)
    float* out = (float*)d_out;

    float* Ek = (float*)d_ws;                    // B*H*NK floats (transposed)
    float* eq = Ek + (size_t)B * H * NK;         // B*NQ*H floats

    const int proj_blocks = (B * NK + B * NQ) / 8;   // 512
    proj_kernel<<<proj_blocks, 256, 0, stream>>>(keys, queries, Wk, Wq, b1, Ek, eq);
    attend_kernel<<<B * NQ / G, 512, 0, stream>>>(keys, Ek, eq, w2, out);
}